// Round 4
// baseline (1093.371 us; speedup 1.0000x reference)
//
#include <hip/hip_runtime.h>
#include <cmath>

#define B_ 4
#define T_ 4096
#define D_ 1024

typedef __attribute__((ext_vector_type(4))) float f32x4;
typedef __attribute__((ext_vector_type(2))) float f32x2;
typedef __attribute__((ext_vector_type(8))) short s16x8;

__device__ __forceinline__ f32x4 mfma_bf16(s16x8 a, s16x8 b, f32x4 c) {
    return __builtin_amdgcn_mfma_f32_16x16x32_bf16(a, b, c, 0, 0, 0);
}
__device__ __forceinline__ unsigned short f2bf(float f) {
    union { float f; unsigned int u; } v; v.f = f;
    unsigned int r = v.u + 0x7FFFu + ((v.u >> 16) & 1u);
    return (unsigned short)(r >> 16);
}

// ---------------- kernel 1: repack fp32 weights to bf16 w_t[p][h][d][i] ----
__global__ __launch_bounds__(256) void k_wtrans(const float* __restrict__ wq,
                                                const float* __restrict__ wk,
                                                const float* __restrict__ wv,
                                                unsigned short* __restrict__ wt) {
    int p = blockIdx.x >> 4;   // 0..2
    int h = blockIdx.x & 15;
    const float* src = (p == 0) ? wq : (p == 1) ? wk : wv;
    unsigned short* dst = wt + (size_t)((p * 16 + h) * 64) * 64;
    for (int idx = threadIdx.x; idx < 64 * 64; idx += 256) {
        int d = idx >> 6, i = idx & 63;
        dst[d * 64 + i] = f2bf(src[i * 1024 + d * 16 + h]);   // w[i][d][h]
    }
}

// ---------------- kernel 2: QKV projection + fused RoPE ---------------------
// block: 256 thr (4 waves), handles (b, head-pair hp, 64 tokens).
// Q_t,K_t: [b][h][t][d] (d-contig).  V_t: [b][h][d][t] (t-contig).  All bf16.
__global__ __launch_bounds__(256) void k_qkv(const float* __restrict__ x,
                                             const unsigned short* __restrict__ wt,
                                             unsigned short* __restrict__ Qt,
                                             unsigned short* __restrict__ Kt,
                                             unsigned short* __restrict__ Vt) {
    int bid = blockIdx.x;
    int b   = bid >> 9;
    int rem = bid & 511;
    int tc  = rem >> 3;         // 0..63 token chunk
    int hp  = rem & 7;          // head pair
    int t0  = tc * 64;
    int tid = threadIdx.x, w = tid >> 6, lane = tid & 63;
    int quad = lane >> 4, l16 = lane & 15;

    __shared__ alignas(16) unsigned short xh[2 * 64 * 72];   // [hh][t][i], pad 72
    __shared__ alignas(16) unsigned short outl[64 * 68];     // staging tile, pad 68

    for (int n = tid; n < 8192; n += 256) {
        int hh = n >> 12, r = n & 4095, t = r >> 6, i = r & 63;
        xh[hh * 4608 + t * 72 + i] =
            f2bf(x[(size_t)(b * T_ + t0 + t) * D_ + i * 16 + (2 * hp + hh)]);
    }
    __syncthreads();

    s16x8 xf[2][2];
    #pragma unroll
    for (int hh = 0; hh < 2; ++hh)
        #pragma unroll
        for (int kc = 0; kc < 2; ++kc)
            xf[hh][kc] = *(const s16x8*)&xh[hh * 4608 + (16 * w + l16) * 72 + kc * 32 + quad * 8];

    f32x4 acc[3][2][4];
    #pragma unroll
    for (int p = 0; p < 3; ++p)
        #pragma unroll
        for (int hh = 0; hh < 2; ++hh)
            #pragma unroll
            for (int nt = 0; nt < 4; ++nt)
                acc[p][hh][nt] = (f32x4){0.f, 0.f, 0.f, 0.f};

    #pragma unroll
    for (int p = 0; p < 3; ++p)
        #pragma unroll
        for (int hh = 0; hh < 2; ++hh)
            #pragma unroll
            for (int nt = 0; nt < 4; ++nt)
                #pragma unroll
                for (int kc = 0; kc < 2; ++kc) {
                    const s16x8 wf = *(const s16x8*)&wt[
                        (size_t)((p * 16 + 2 * hp + hh) * 64 + nt * 16 + l16) * 64 + kc * 32 + quad * 8];
                    if (p < 2)  // Q,K: C[t][d] = X[t][i] * W[i][d]
                        acc[p][hh][nt] = mfma_bf16(xf[hh][kc], wf, acc[p][hh][nt]);
                    else        // V: C[d][t] = W^T[d][i] * X^T[i][t]
                        acc[p][hh][nt] = mfma_bf16(wf, xf[hh][kc], acc[p][hh][nt]);
                }

    // fused RoPE on Q,K: pairs (d, h0)<->(d, h0+1), j = d*8 + hp
    #pragma unroll
    for (int nt = 0; nt < 4; ++nt) {
        int d = nt * 16 + l16;
        float f = exp2f((float)(d * 8 + hp) * -0.02595256324130751f); // -log2(1e4)/512
        #pragma unroll
        for (int r = 0; r < 4; ++r) {
            float ang = (float)(t0 + 16 * w + quad * 4 + r) * f;
            float s, c;
            sincosf(ang, &s, &c);
            float a0 = acc[0][0][nt][r], a1 = acc[0][1][nt][r];
            acc[0][0][nt][r] = a0 * c - a1 * s;
            acc[0][1][nt][r] = a0 * s + a1 * c;
            float k0 = acc[1][0][nt][r], k1 = acc[1][1][nt][r];
            acc[1][0][nt][r] = k0 * c - k1 * s;
            acc[1][1][nt][r] = k0 * s + k1 * c;
        }
    }

    // store 6 tiles (Q,K as [t][d]; V as [d][t]) via LDS for coalescing
    #pragma unroll
    for (int p = 0; p < 3; ++p)
        #pragma unroll
        for (int hh = 0; hh < 2; ++hh) {
            __syncthreads();
            if (p < 2) {
                #pragma unroll
                for (int nt = 0; nt < 4; ++nt)
                    #pragma unroll
                    for (int r = 0; r < 4; ++r)
                        outl[(16 * w + quad * 4 + r) * 68 + nt * 16 + l16] = f2bf(acc[p][hh][nt][r]);
            } else {
                #pragma unroll
                for (int mt = 0; mt < 4; ++mt)
                    #pragma unroll
                    for (int r = 0; r < 4; ++r)
                        outl[(mt * 16 + quad * 4 + r) * 68 + 16 * w + l16] = f2bf(acc[p][hh][mt][r]);
            }
            __syncthreads();
            int h = 2 * hp + hh;
            if (p < 2) {
                unsigned short* g = (p == 0 ? Qt : Kt) + ((size_t)(b * 16 + h) * T_ + t0) * 64;
                for (int n = 2 * tid; n < 4096; n += 512) {
                    int t = n >> 6, dd = n & 63;
                    *(unsigned int*)(g + n) = *(const unsigned int*)&outl[t * 68 + dd];
                }
            } else {
                unsigned short* g = Vt + (size_t)(b * 16 + h) * 64 * T_;
                for (int n = 2 * tid; n < 4096; n += 512) {
                    int d = n >> 6, tt = n & 63;
                    *(unsigned int*)(g + d * T_ + t0 + tt) = *(const unsigned int*)&outl[d * 68 + tt];
                }
            }
        }
}

// ---------------- kernel 3: flash attention -------------------------------
// block: 512 thr (8 waves), 32 q-rows. Wave w owns d-slice [128w,128w+128) = 2 heads.
__global__ __launch_bounds__(512) void k_attn(const unsigned short* __restrict__ Qt,
                                              const unsigned short* __restrict__ Kt,
                                              const unsigned short* __restrict__ Vt,
                                              float* __restrict__ out) {
    int bid = blockIdx.x;
    int j = bid >> 2, b = bid & 3;
    int qt = (bid < 256) ? (127 - j) : (j - 64);   // heavy blocks first (causal balance)
    int q0 = qt * 32;
    int tid = threadIdx.x, w = tid >> 6, lane = tid & 63;
    int quad = lane >> 4, l16 = lane & 15;

    __shared__ alignas(16) float S_red[8][32][36];          // partial S^T per wave, padded
    __shared__ alignas(16) unsigned short P_lds[32][40];    // P[q][kpos] bf16, padded
    __shared__ float m_st[32], l_st[32], alpha_s[32];

    if (tid < 32) { m_st[tid] = -INFINITY; l_st[tid] = 0.f; }

    // Q fragments (loop-invariant): B-operand, [q][d] d-contig
    s16x8 qf[2][4];
    #pragma unroll
    for (int qs = 0; qs < 2; ++qs)
        #pragma unroll
        for (int c = 0; c < 4; ++c) {
            int dg = w * 128 + c * 32 + quad * 8;
            int head = dg >> 6, d64 = dg & 63;
            qf[qs][c] = *(const s16x8*)&Qt[((size_t)(b * 16 + head) * T_ + q0 + qs * 16 + l16) * 64 + d64];
        }

    f32x4 Y[8][2];
    #pragma unroll
    for (int mt = 0; mt < 8; ++mt) { Y[mt][0] = (f32x4){0,0,0,0}; Y[mt][1] = (f32x4){0,0,0,0}; }

    __syncthreads();

    const float gamma = 0.03125f;   // 1/sqrt(1024)
    int rq = tid >> 4;              // reduction-phase row 0..31 (16 lanes per row, same wave)
    int kk = (tid & 15) * 2;
    int nkt = qt + 1;

    for (int kt = 0; kt < nkt; ++kt) {
        int kbase = kt * 32;
        // ---- S^T partial over wave's 128 d: A=K, B=Q ----
        f32x4 S[2][2];
        S[0][0] = (f32x4){0,0,0,0}; S[0][1] = (f32x4){0,0,0,0};
        S[1][0] = (f32x4){0,0,0,0}; S[1][1] = (f32x4){0,0,0,0};
        #pragma unroll
        for (int kps = 0; kps < 2; ++kps)
            #pragma unroll
            for (int c = 0; c < 4; ++c) {
                int dg = w * 128 + c * 32 + quad * 8;
                int head = dg >> 6, d64 = dg & 63;
                s16x8 kf = *(const s16x8*)&Kt[((size_t)(b * 16 + head) * T_ + kbase + kps * 16 + l16) * 64 + d64];
                S[kps][0] = mfma_bf16(kf, qf[0][c], S[kps][0]);
                S[kps][1] = mfma_bf16(kf, qf[1][c], S[kps][1]);
            }
        #pragma unroll
        for (int kps = 0; kps < 2; ++kps)
            #pragma unroll
            for (int qs = 0; qs < 2; ++qs)
                *(f32x4*)&S_red[w][qs * 16 + l16][kps * 16 + quad * 4] = S[kps][qs];
        __syncthreads();

        // ---- reduce across 8 waves + online softmax ----
        float s0 = 0.f, s1 = 0.f;
        #pragma unroll
        for (int sl = 0; sl < 8; ++sl) {
            f32x2 v = *(const f32x2*)&S_red[sl][rq][kk];
            s0 += v.x; s1 += v.y;
        }
        s0 *= gamma; s1 *= gamma;
        int qg = q0 + rq;
        if (kbase + kk > qg)     s0 = -INFINITY;
        if (kbase + kk + 1 > qg) s1 = -INFINITY;
        float mx = fmaxf(s0, s1);
        mx = fmaxf(mx, __shfl_xor(mx, 1));
        mx = fmaxf(mx, __shfl_xor(mx, 2));
        mx = fmaxf(mx, __shfl_xor(mx, 4));
        mx = fmaxf(mx, __shfl_xor(mx, 8));
        float m_old = m_st[rq];
        float m_new = fmaxf(m_old, mx);
        float alpha = __expf(m_old - m_new);
        float p0 = __expf(s0 - m_new), p1 = __expf(s1 - m_new);
        float ps = p0 + p1;
        ps += __shfl_xor(ps, 1); ps += __shfl_xor(ps, 2);
        ps += __shfl_xor(ps, 4); ps += __shfl_xor(ps, 8);
        if ((tid & 15) == 0) {
            l_st[rq] = alpha * l_st[rq] + ps;
            m_st[rq] = m_new;
            alpha_s[rq] = alpha;
        }
        unsigned int pp = (unsigned int)f2bf(p0) | ((unsigned int)f2bf(p1) << 16);
        *(unsigned int*)&P_lds[rq][kk] = pp;
        __syncthreads();

        // ---- PV: A = V^T (16B loads from [d][t]), B = P^T from LDS ----
        float a0 = alpha_s[l16], a1 = alpha_s[16 + l16];
        s16x8 pf0 = *(const s16x8*)&P_lds[l16][quad * 8];
        s16x8 pf1 = *(const s16x8*)&P_lds[16 + l16][quad * 8];
        #pragma unroll
        for (int mt = 0; mt < 8; ++mt) {
            int dg = w * 128 + mt * 16 + l16;
            int head = dg >> 6, d64 = dg & 63;
            s16x8 vf = *(const s16x8*)&Vt[((size_t)(b * 16 + head) * 64 + d64) * T_ + kbase + quad * 8];
            Y[mt][0] *= a0;
            Y[mt][1] *= a1;
            Y[mt][0] = mfma_bf16(vf, pf0, Y[mt][0]);
            Y[mt][1] = mfma_bf16(vf, pf1, Y[mt][1]);
        }
    }

    // ---- epilogue: normalize, map d->(h,d64)->e, store fp32 ----
    float inv0 = 1.f / l_st[l16], inv1 = 1.f / l_st[16 + l16];
    #pragma unroll
    for (int mt = 0; mt < 8; ++mt)
        #pragma unroll
        for (int r = 0; r < 4; ++r) {
            int dg = w * 128 + mt * 16 + quad * 4 + r;
            int head = dg >> 6, d64 = dg & 63;
            int e = d64 * 16 + head;
            out[(size_t)(b * T_ + q0 + l16) * D_ + e]      = Y[mt][0][r] * inv0;
            out[(size_t)(b * T_ + q0 + 16 + l16) * D_ + e] = Y[mt][1][r] * inv1;
        }
}

extern "C" void kernel_launch(void* const* d_in, const int* in_sizes, int n_in,
                              void* d_out, int out_size, void* d_ws, size_t ws_size,
                              hipStream_t stream) {
    const float* x  = (const float*)d_in[0];
    const float* wq = (const float*)d_in[1];
    const float* wk = (const float*)d_in[2];
    const float* wv = (const float*)d_in[3];
    unsigned short* ws = (unsigned short*)d_ws;

    // workspace layout (bf16 elements)
    const size_t WT_ELEMS  = 3 * 16 * 64 * 64;          // 196608
    const size_t QKV_ELEMS = (size_t)B_ * 16 * T_ * 64; // 16777216 each
    const size_t NEED_BYTES = (WT_ELEMS + 3 * QKV_ELEMS) * sizeof(unsigned short);

    // Guard (graph-capture-safe constant branch): round-1 evidence shows the
    // full ~101 MB workspace is backed, so this never triggers; kept as a
    // tripwire against harness changes.
    if (ws_size < NEED_BYTES) return;

    unsigned short* wt = ws;
    unsigned short* Qt = ws + WT_ELEMS;
    unsigned short* Kt = Qt + QKV_ELEMS;
    unsigned short* Vt = Kt + QKV_ELEMS;
    float* outp = (float*)d_out;

    k_wtrans<<<48, 256, 0, stream>>>(wq, wk, wv, wt);
    k_qkv<<<2048, 256, 0, stream>>>(x, wt, Qt, Kt, Vt);
    k_attn<<<512, 512, 0, stream>>>(Qt, Kt, Vt, outp);
}